// Round 9
// baseline (157.465 us; speedup 1.0000x reference)
//
#include <hip/hip_runtime.h>

// SparseLoRAMoE — SINGLE fused kernel, expert-pair-grouped.
// Rounds 2-8 used k1(bucket)/k2(stage A)/k3(stage B): totals pinned at
// ~65us of kernel+gap time regardless of k2 surgery. Fusing kills the two
// launch gaps, the k1 kernel, and the acts global round-trip (512KB W+R).
//   Block = (ordered expert pair pb, d-half). 512 blocks x 512 threads.
//   1. scan idxs (32KB, L2) -> this pair's tokens in LDS (self-bucketing)
//   2. stage A (r4-proven loop): waves 0-3 = e0, waves 4-7 = e1; each wave
//      4 tokens x 16 ranks, acc[64], 16 wa float4 issue-then-consume,
//      x prefetched one K-step ahead; butterfly; silu -> LDS sacts[m][32]
//      (chunks of 16 tokens if m>16). acts NEVER touch global.
//   3. stage B: thread covers cols d0=dhalf*1024+tid, d1=d0+512; wb cols of
//      both experts in 64 VGPRs reused over bucket; non-temporal stores;
//      out written exactly once. Stage A duplicated per d-half: +0.5 GFLOP
//      (total 1.6 GF ~ 10us FMA floor) for 2x parallelism.
//   Grid: bid = dhalf*256 + pb -> pair's two blocks are 256 apart = same
//   XCD (256%8==0), sharing wa/wb in one L2.
// No workspace use, no atomics on out, bit-deterministic.

#define NDIM   2048
#define RANK   16
#define NEXP   16
#define TOKENS 4096
#define CAP_P  64       // tokens per pair; mean 16, sd ~4 -> +12 sigma
#define BLOCK  512

#define DOT4(a, b) ((a).x*(b).x + (a).y*(b).y + (a).z*(b).z + (a).w*(b).w)

__global__ __launch_bounds__(BLOCK, 2) void fused_moe(
    const float* __restrict__ x,        // [T, 2048]
    const float* __restrict__ routing,  // [T, 2]
    const int*   __restrict__ idxs,     // [T, 2]
    const float* __restrict__ wa,       // [16, 16, 2048]
    const float* __restrict__ wb,       // [16, 2048, 16]
    float* __restrict__ out)            // [T, 2048]
{
    const int pb    = blockIdx.x & 255;         // ordered pair (e0,e1)
    const int dhalf = blockIdx.x >> 8;          // 0 or 1
    const int e0 = pb >> 4, e1 = pb & (NEXP - 1);
    const int tid  = threadIdx.x;
    const int lane = tid & 63;
    const int wave = tid >> 6;                  // 0..7

    __shared__ int   stok[CAP_P];
    __shared__ float srout[CAP_P][2];
    __shared__ __align__(16) float sacts[CAP_P][2 * RANK];   // 8 KB
    __shared__ int scnt;
    if (tid == 0) scnt = 0;
    __syncthreads();

    // ---- 1. self-bucketing: scan idxs for tokens with (e0,e1) == pb ----
    const int2* p2 = (const int2*)idxs;
    for (int t = tid; t < TOKENS; t += BLOCK) {
        int2 v = p2[t];
        if (v.x == e0 && v.y == e1) {
            int p = atomicAdd(&scnt, 1);
            if (p < CAP_P) {
                stok[p] = t;
                srout[p][0] = routing[2 * t];
                srout[p][1] = routing[2 * t + 1];
            }
        }
    }
    __syncthreads();
    int m = scnt;
    if (m > CAP_P) m = CAP_P;
    if (m == 0) return;

    // ---- 2. stage A: waves 0-3 -> e0, waves 4-7 -> e1; 4 tokens/wave ----
    const int eflag = wave >> 2;                // 0: e0 half, 1: e1 half
    const int wgrp  = wave & 3;                 // token subgroup
    const int myexp = eflag ? e1 : e0;
    const float* wbase = wa + (size_t)myexp * RANK * NDIM + lane * 4;

    for (int cbase = 0; cbase < m; cbase += 16) {   // chunks of 16 tokens
        const float* xp[4];
        #pragma unroll
        for (int j = 0; j < 4; j++) {
            int idx = cbase + 4 * wgrp + j;
            if (idx >= m) idx = m - 1;          // duplicate last (same-value write)
            xp[j] = x + (size_t)stok[idx] * NDIM + lane * 4;
        }

        float acc[64];
        #pragma unroll
        for (int i = 0; i < 64; i++) acc[i] = 0.f;

        float4 xc[4], xn[4];
        #pragma unroll
        for (int j = 0; j < 4; j++) xc[j] = *(const float4*)(xp[j]);

        #pragma unroll 2
        for (int s = 0; s < NDIM / 256; s++) {  // 8 K-steps, lanes split K
            if (s < NDIM / 256 - 1) {           // prefetch next x step
                #pragma unroll
                for (int j = 0; j < 4; j++)
                    xn[j] = *(const float4*)(xp[j] + (s + 1) * 256);
            }
            const float* wstep = wbase + s * 256;
            float4 wv[16];
            #pragma unroll
            for (int r = 0; r < RANK; r++)      // issue all 16 wa loads...
                wv[r] = *(const float4*)(wstep + r * NDIM);
            #pragma unroll
            for (int r = 0; r < RANK; r++) {    // ...consume (progressive vmcnt)
                acc[r]      += DOT4(xc[0], wv[r]);
                acc[16 + r] += DOT4(xc[1], wv[r]);
                acc[32 + r] += DOT4(xc[2], wv[r]);
                acc[48 + r] += DOT4(xc[3], wv[r]);
            }
            #pragma unroll
            for (int j = 0; j < 4; j++) xc[j] = xn[j];
        }

        // 64-value -> per-lane halving butterfly (static indices)
        #pragma unroll
        for (int mw = 32; mw >= 1; mw >>= 1) {
            const bool up = (lane & mw) != 0;
            #pragma unroll
            for (int i = 0; i < mw; i++) {
                float lo = acc[i], hi = acc[i + mw];
                float mine = up ? hi : lo;
                float give = up ? lo : hi;
                acc[i] = mine + __shfl_xor(give, mw, 64);
            }
        }
        // lane l: token chunk idx cbase+4*wgrp+(l>>4), rank l&15
        float v  = acc[0];
        float sv = v / (1.f + __expf(-v));      // silu
        int idx  = cbase + 4 * wgrp + (lane >> 4);
        if (idx >= m) idx = m - 1;              // duplicate writes same value
        sacts[idx][(lane & 15) + 16 * eflag] = sv;
    }
    __syncthreads();

    // ---- 3. stage B: 2 cols/thread in this d-half, wb in 64 VGPRs ----
    const int d0 = (dhalf << 10) + tid;         // [dhalf*1024, dhalf*1024+512)
    const int d1 = d0 + 512;

    const float4* p00 = (const float4*)(wb + ((size_t)e0 * NDIM + d0) * RANK);
    const float4* p01 = (const float4*)(wb + ((size_t)e0 * NDIM + d1) * RANK);
    const float4* p10 = (const float4*)(wb + ((size_t)e1 * NDIM + d0) * RANK);
    const float4* p11 = (const float4*)(wb + ((size_t)e1 * NDIM + d1) * RANK);
    const float4 a00 = p00[0], a01 = p00[1], a02 = p00[2], a03 = p00[3];
    const float4 b00 = p01[0], b01 = p01[1], b02 = p01[2], b03 = p01[3];
    const float4 a10 = p10[0], a11 = p10[1], a12 = p10[2], a13 = p10[3];
    const float4 b10 = p11[0], b11 = p11[1], b12 = p11[2], b13 = p11[3];

    #pragma unroll 2
    for (int i = 0; i < m; i++) {
        const float4* a = (const float4*)sacts[i];      // LDS broadcast reads
        float4 A0 = a[0], A1 = a[1], A2 = a[2], A3 = a[3];
        float4 B0 = a[4], B1 = a[5], B2 = a[6], B3 = a[7];
        float s0_0 = DOT4(a00, A0) + DOT4(a01, A1) + DOT4(a02, A2) + DOT4(a03, A3);
        float s1_0 = DOT4(a10, B0) + DOT4(a11, B1) + DOT4(a12, B2) + DOT4(a13, B3);
        float s0_1 = DOT4(b00, A0) + DOT4(b01, A1) + DOT4(b02, A2) + DOT4(b03, A3);
        float s1_1 = DOT4(b10, B0) + DOT4(b11, B1) + DOT4(b12, B2) + DOT4(b13, B3);
        const float r0 = srout[i][0], r1 = srout[i][1];
        float* op = out + (size_t)stok[i] * NDIM;
        __builtin_nontemporal_store(2.0f * (r0 * s0_0 + r1 * s1_0), op + d0);
        __builtin_nontemporal_store(2.0f * (r0 * s0_1 + r1 * s1_1), op + d1);
    }
}

extern "C" void kernel_launch(void* const* d_in, const int* in_sizes, int n_in,
                              void* d_out, int out_size, void* d_ws, size_t ws_size,
                              hipStream_t stream) {
    const float* x       = (const float*)d_in[0];
    const float* routing = (const float*)d_in[1];
    const int*   idxs    = (const int*)  d_in[2];
    const float* wa      = (const float*)d_in[3];
    const float* wb      = (const float*)d_in[4];
    float*       out     = (float*)d_out;

    fused_moe<<<512, BLOCK, 0, stream>>>(x, routing, idxs, wa, wb, out);
}

// Round 11
// 141.455 us; speedup vs baseline: 1.1132x; 1.1132x over previous
//
#include <hip/hip_runtime.h>

// SparseLoRAMoE — SINGLE fused kernel, block = one ordered expert pair.
// [Round 11 = round 10 RESUBMIT: the r10 bench died to an infra failure
//  ("container failed twice") with no measurement; kernel unchanged so the
//  r9->r10 A/B (register cap + stage-A dedup) stays clean.]
// r9 post-mortem: (512,2) resolved to a 128-VGPR cap -> compiler broke the
// acc[64]+wv[16]+prefetch schedule (VGPR=104); and the per-d-half split
// duplicated stage A (FETCH 61MB = x read twice, 2x FMA).
// r10: 256 blocks x 512 thr, __launch_bounds__(512,1) -> 256-VGPR budget
// under either launch-bounds semantics; stage A computed ONCE per pair;
// stage B loops two 1024-col groups (wb reloaded between groups).
//   1. scan idxs (32KB, L2) -> pair's tokens/routing in LDS
//   2. stage A (r4 loop): waves 0-3 e0, waves 4-7 e1; wave owns 4 tokens x
//      16 ranks, acc[64], 16 wa float4 issue-then-consume, x prefetched one
//      K-step ahead; 64-lane butterfly; silu -> LDS sacts (never global)
//   3. stage B: per group g in {0,1}: thread covers d0=g*1024+tid, d1=d0+512;
//      wb cols of both experts in 64 VGPRs; NT stores; out written once.
// No workspace, no atomics on out, bit-deterministic.

#define NDIM   2048
#define RANK   16
#define NEXP   16
#define TOKENS 4096
#define CAP_P  64       // tokens per pair; mean 16, sd ~4 -> +12 sigma
#define BLOCK  512

#define DOT4(a, b) ((a).x*(b).x + (a).y*(b).y + (a).z*(b).z + (a).w*(b).w)

__global__ __launch_bounds__(BLOCK, 1) void fused_moe(
    const float* __restrict__ x,        // [T, 2048]
    const float* __restrict__ routing,  // [T, 2]
    const int*   __restrict__ idxs,     // [T, 2]
    const float* __restrict__ wa,       // [16, 16, 2048]
    const float* __restrict__ wb,       // [16, 2048, 16]
    float* __restrict__ out)            // [T, 2048]
{
    const int pb = blockIdx.x;                  // ordered pair (e0,e1)
    const int e0 = pb >> 4, e1 = pb & (NEXP - 1);
    const int tid  = threadIdx.x;
    const int lane = tid & 63;
    const int wave = tid >> 6;                  // 0..7

    __shared__ int   stok[CAP_P];
    __shared__ float srout[CAP_P][2];
    __shared__ __align__(16) float sacts[CAP_P][2 * RANK];   // 8 KB
    __shared__ int scnt;
    if (tid == 0) scnt = 0;
    __syncthreads();

    // ---- 1. self-bucketing: scan idxs for tokens with (e0,e1) == pb ----
    const int2* p2 = (const int2*)idxs;
    for (int t = tid; t < TOKENS; t += BLOCK) {
        int2 v = p2[t];
        if (v.x == e0 && v.y == e1) {
            int p = atomicAdd(&scnt, 1);
            if (p < CAP_P) {
                stok[p] = t;
                srout[p][0] = routing[2 * t];
                srout[p][1] = routing[2 * t + 1];
            }
        }
    }
    __syncthreads();
    int m = scnt;
    if (m > CAP_P) m = CAP_P;
    if (m == 0) return;

    // ---- 2. stage A: waves 0-3 -> e0, waves 4-7 -> e1; 4 tokens/wave ----
    const int eflag = wave >> 2;                // 0: e0 half, 1: e1 half
    const int wgrp  = wave & 3;                 // token subgroup
    const int myexp = eflag ? e1 : e0;
    const float* wbase = wa + (size_t)myexp * RANK * NDIM + lane * 4;

    for (int cbase = 0; cbase < m; cbase += 16) {   // chunks of 16 tokens
        const float* xp[4];
        #pragma unroll
        for (int j = 0; j < 4; j++) {
            int idx = cbase + 4 * wgrp + j;
            if (idx >= m) idx = m - 1;          // duplicate last (same-value write)
            xp[j] = x + (size_t)stok[idx] * NDIM + lane * 4;
        }

        float acc[64];
        #pragma unroll
        for (int i = 0; i < 64; i++) acc[i] = 0.f;

        float4 xc[4], xn[4];
        #pragma unroll
        for (int j = 0; j < 4; j++) xc[j] = *(const float4*)(xp[j]);

        #pragma unroll 2
        for (int s = 0; s < NDIM / 256; s++) {  // 8 K-steps, lanes split K
            if (s < NDIM / 256 - 1) {           // prefetch next x step
                #pragma unroll
                for (int j = 0; j < 4; j++)
                    xn[j] = *(const float4*)(xp[j] + (s + 1) * 256);
            }
            const float* wstep = wbase + s * 256;
            float4 wv[16];
            #pragma unroll
            for (int r = 0; r < RANK; r++)      // issue all 16 wa loads...
                wv[r] = *(const float4*)(wstep + r * NDIM);
            #pragma unroll
            for (int r = 0; r < RANK; r++) {    // ...consume (progressive vmcnt)
                acc[r]      += DOT4(xc[0], wv[r]);
                acc[16 + r] += DOT4(xc[1], wv[r]);
                acc[32 + r] += DOT4(xc[2], wv[r]);
                acc[48 + r] += DOT4(xc[3], wv[r]);
            }
            #pragma unroll
            for (int j = 0; j < 4; j++) xc[j] = xn[j];
        }

        // 64-value -> per-lane halving butterfly (static indices)
        #pragma unroll
        for (int mw = 32; mw >= 1; mw >>= 1) {
            const bool up = (lane & mw) != 0;
            #pragma unroll
            for (int i = 0; i < mw; i++) {
                float lo = acc[i], hi = acc[i + mw];
                float mine = up ? hi : lo;
                float give = up ? lo : hi;
                acc[i] = mine + __shfl_xor(give, mw, 64);
            }
        }
        // lane l: token chunk idx cbase+4*wgrp+(l>>4), rank l&15
        float v  = acc[0];
        float sv = v / (1.f + __expf(-v));      // silu
        int idx  = cbase + 4 * wgrp + (lane >> 4);
        if (idx >= m) idx = m - 1;              // duplicate writes same value
        sacts[idx][(lane & 15) + 16 * eflag] = sv;
    }
    __syncthreads();

    // ---- 3. stage B: 2 col-groups x 2 cols/thread, wb in 64 VGPRs/group ----
    #pragma unroll
    for (int g = 0; g < 2; g++) {
        const int d0 = (g << 10) + tid;         // [g*1024, g*1024+512)
        const int d1 = d0 + 512;

        const float4* p00 = (const float4*)(wb + ((size_t)e0 * NDIM + d0) * RANK);
        const float4* p01 = (const float4*)(wb + ((size_t)e0 * NDIM + d1) * RANK);
        const float4* p10 = (const float4*)(wb + ((size_t)e1 * NDIM + d0) * RANK);
        const float4* p11 = (const float4*)(wb + ((size_t)e1 * NDIM + d1) * RANK);
        const float4 a00 = p00[0], a01 = p00[1], a02 = p00[2], a03 = p00[3];
        const float4 b00 = p01[0], b01 = p01[1], b02 = p01[2], b03 = p01[3];
        const float4 a10 = p10[0], a11 = p10[1], a12 = p10[2], a13 = p10[3];
        const float4 b10 = p11[0], b11 = p11[1], b12 = p11[2], b13 = p11[3];

        #pragma unroll 2
        for (int i = 0; i < m; i++) {
            const float4* a = (const float4*)sacts[i];      // LDS broadcast reads
            float4 A0 = a[0], A1 = a[1], A2 = a[2], A3 = a[3];
            float4 B0 = a[4], B1 = a[5], B2 = a[6], B3 = a[7];
            float s0_0 = DOT4(a00, A0) + DOT4(a01, A1) + DOT4(a02, A2) + DOT4(a03, A3);
            float s1_0 = DOT4(a10, B0) + DOT4(a11, B1) + DOT4(a12, B2) + DOT4(a13, B3);
            float s0_1 = DOT4(b00, A0) + DOT4(b01, A1) + DOT4(b02, A2) + DOT4(b03, A3);
            float s1_1 = DOT4(b10, B0) + DOT4(b11, B1) + DOT4(b12, B2) + DOT4(b13, B3);
            const float r0 = srout[i][0], r1 = srout[i][1];
            float* op = out + (size_t)stok[i] * NDIM;
            __builtin_nontemporal_store(2.0f * (r0 * s0_0 + r1 * s1_0), op + d0);
            __builtin_nontemporal_store(2.0f * (r0 * s0_1 + r1 * s1_1), op + d1);
        }
    }
}

extern "C" void kernel_launch(void* const* d_in, const int* in_sizes, int n_in,
                              void* d_out, int out_size, void* d_ws, size_t ws_size,
                              hipStream_t stream) {
    const float* x       = (const float*)d_in[0];
    const float* routing = (const float*)d_in[1];
    const int*   idxs    = (const int*)  d_in[2];
    const float* wa      = (const float*)d_in[3];
    const float* wb      = (const float*)d_in[4];
    float*       out     = (float*)d_out;

    fused_moe<<<NEXP * NEXP, BLOCK, 0, stream>>>(x, routing, idxs, wa, wb, out);
}

// Round 12
// 131.564 us; speedup vs baseline: 1.1969x; 1.0752x over previous
//
#include <hip/hip_runtime.h>

// SparseLoRAMoE, expert-grouped, atomic-free — TLP-first stage A.
// r11 verdict: VGPR stayed 104 under (512,1) -> compiler VOLUNTARILY sinks
// the 16 wa loads regardless of budget; ILP-per-wave is ceilinged. The wall
// is waves/SIMD. r12: wave tile halved along ranks -> 4 entries x 8 ranks:
// acc[32]+wv[8]+x ping-pong ~110 VGPR, honest fit in (256,4)'s 128-reg cap,
// 4 waves/SIMD (2x r7), same wa arithmetic intensity as r4 (16 FMA/float4;
// r6's failed E=2 had 8). Block = 8 entries (2 entry-grps x 2 rank-halves),
// grid 1536 -> ~4-6 blocks/CU resident.
//   K1 (272 blocks): per-bucket scan of idxs, LDS counter, no global atomics.
//   K2 (1536 blocks, (256,4)): acts[ent][16] = silu(x . wa[e]^T); lanes split
//       K (coalesced); 8 K-steps: 4 x loads (prefetch) + 8 wa loads + 128 FMA;
//       32-value butterfly -> lane<32 writes (entry lane>>3, rank lane&7).
//   K3 (1024 blocks): 2 cols/thread, LDS-staged bucket, NT stores (r7 verbatim).
// No zeroing, no atomics on out, bit-deterministic.

#define NDIM   2048
#define RANK   16
#define NEXP   16
#define TOKENS 4096
#define CAP_E  768      // per-expert entries; mean 512, sd ~22 -> +11 sigma
#define CAP_P  64       // per-pair tokens;   mean 16,  sd ~4  -> +12 sigma
#define TILE_E 8        // entries per K2 block (2 entry-groups x 4)
#define ETILES (CAP_E / TILE_E)   // 96

#define DOT4(a, b) ((a).x*(b).x + (a).y*(b).y + (a).z*(b).z + (a).w*(b).w)

// ---------------- K1: bucketing, one block per bucket ----------------
__global__ __launch_bounds__(256) void k1_bucket(const int* __restrict__ idxs,
                                                 int* __restrict__ cntE,
                                                 int* __restrict__ cntP,
                                                 int* __restrict__ bucketE,
                                                 int* __restrict__ bucketP) {
    __shared__ int lcnt;
    const int bid = blockIdx.x;
    const int tid = threadIdx.x;
    if (tid == 0) lcnt = 0;
    __syncthreads();

    if (bid < NEXP) {                       // expert bucket: entries i with idxs[i]==e
        const int e = bid;
        const int4* p4 = (const int4*)idxs; // 8192 ints -> 2048 int4
        int* bk = bucketE + e * CAP_E;
        for (int i = tid; i < TOKENS * 2 / 4; i += 256) {
            int4 v = p4[i];
            if (v.x == e) { int p = atomicAdd(&lcnt, 1); if (p < CAP_E) bk[p] = 4*i+0; }
            if (v.y == e) { int p = atomicAdd(&lcnt, 1); if (p < CAP_E) bk[p] = 4*i+1; }
            if (v.z == e) { int p = atomicAdd(&lcnt, 1); if (p < CAP_E) bk[p] = 4*i+2; }
            if (v.w == e) { int p = atomicAdd(&lcnt, 1); if (p < CAP_E) bk[p] = 4*i+3; }
        }
        __syncthreads();
        if (tid == 0) cntE[e] = lcnt < CAP_E ? lcnt : CAP_E;
    } else {                                // pair bucket: tokens t with (e0,e1)==pb
        const int pb = bid - NEXP;
        const int e0 = pb >> 4, e1 = pb & (NEXP - 1);
        const int2* p2 = (const int2*)idxs;
        int* bk = bucketP + pb * CAP_P;
        for (int t = tid; t < TOKENS; t += 256) {
            int2 v = p2[t];
            if (v.x == e0 && v.y == e1) {
                int p = atomicAdd(&lcnt, 1);
                if (p < CAP_P) bk[p] = t;
            }
        }
        __syncthreads();
        if (tid == 0) cntP[pb] = lcnt < CAP_P ? lcnt : CAP_P;
    }
}

// ---------------- K2: stage A, wave = 4 entries x 8 ranks, 4 waves/SIMD ----------------
__global__ __launch_bounds__(256, 4) void k2_stage_a(const float* __restrict__ x,
                                                     const float* __restrict__ wa,
                                                     const int* __restrict__ cntE,
                                                     const int* __restrict__ bucketE,
                                                     float* __restrict__ acts) {
    const int e    = blockIdx.x & (NEXP - 1);
    const int tile = blockIdx.x >> 4;           // 0..ETILES-1
    int n = cntE[e];
    const int start = tile * TILE_E;
    int m = n - start;
    if (m <= 0) return;
    if (m > TILE_E) m = TILE_E;

    __shared__ int sTok[TILE_E];
    const int tid    = threadIdx.x;
    const int lane   = tid & 63;
    const int wave   = tid >> 6;                // 0..3
    const int entgrp = wave & 1;                // entries 4*entgrp .. +3
    const int rhalf  = wave >> 1;               // ranks 8*rhalf .. +7

    if (tid < TILE_E) {
        int src = tid < m ? tid : m - 1;        // duplicate last entry in short tiles
        sTok[tid] = bucketE[e * CAP_E + start + src];
    }
    __syncthreads();                            // the only barrier

    const float* xp[4];
    #pragma unroll
    for (int j = 0; j < 4; j++)
        xp[j] = x + (size_t)(sTok[entgrp * 4 + j] >> 1) * NDIM + lane * 4;
    const float* wbase = wa + ((size_t)e * RANK + rhalf * 8) * NDIM + lane * 4;

    float acc[32];                              // [entry 0..3][rank 0..7]
    #pragma unroll
    for (int i = 0; i < 32; i++) acc[i] = 0.f;

    float4 xc[4], xn[4];
    #pragma unroll
    for (int j = 0; j < 4; j++) xc[j] = *(const float4*)(xp[j]);

    for (int s = 0; s < NDIM / 256; s++) {      // 8 K-steps, lanes split K
        if (s < NDIM / 256 - 1) {               // prefetch next x step (HBM stream)
            #pragma unroll
            for (int j = 0; j < 4; j++)
                xn[j] = *(const float4*)(xp[j] + (s + 1) * 256);
        }
        const float* wstep = wbase + s * 256;
        float4 wv[8];
        #pragma unroll
        for (int r = 0; r < 8; r++)             // issue all 8 wa loads...
            wv[r] = *(const float4*)(wstep + r * NDIM);
        #pragma unroll
        for (int r = 0; r < 8; r++) {           // ...consume (progressive vmcnt)
            acc[r]      += DOT4(xc[0], wv[r]);
            acc[8 + r]  += DOT4(xc[1], wv[r]);
            acc[16 + r] += DOT4(xc[2], wv[r]);
            acc[24 + r] += DOT4(xc[3], wv[r]);
        }
        #pragma unroll
        for (int j = 0; j < 4; j++) xc[j] = xn[j];
    }

    // ---- reduce 32 values over 64 lanes; lane<32 ends with flat index lane ----
    #pragma unroll
    for (int i = 0; i < 32; i++) acc[i] += __shfl_xor(acc[i], 32, 64);
    #pragma unroll
    for (int mw = 16; mw >= 1; mw >>= 1) {      // halving butterfly (static indices)
        const bool up = (lane & mw) != 0;
        #pragma unroll
        for (int i = 0; i < mw; i++) {
            float lo = acc[i], hi = acc[i + mw];
            float mine = up ? hi : lo;
            float give = up ? lo : hi;
            acc[i] = mine + __shfl_xor(give, mw, 64);
        }
    }
    if (lane < 32) {
        float v  = acc[0];
        float sv = v / (1.f + __expf(-v));      // silu
        int ent  = sTok[entgrp * 4 + (lane >> 3)];
        int rank = rhalf * 8 + (lane & 7);
        acts[(size_t)ent * RANK + rank] = sv;
    }
}

// ---------------- K3: stage B, 2 cols/thread, LDS-staged bucket, NT stores ----------------
__global__ __launch_bounds__(256, 2) void k3_stage_b(const float* __restrict__ routing,
                                                     const float* __restrict__ wb,
                                                     const int* __restrict__ cntP,
                                                     const int* __restrict__ bucketP,
                                                     const float* __restrict__ acts,
                                                     float* __restrict__ out) {
    const int pb  = blockIdx.x & (NEXP * NEXP - 1);
    const int dch = blockIdx.x >> 8;            // 0..3 (512 cols per block)
    int m = cntP[pb];
    if (m <= 0) return;
    if (m > CAP_P) m = CAP_P;
    const int e0 = pb >> 4;
    const int e1 = pb & (NEXP - 1);
    const int tid = threadIdx.x;
    const int d0 = dch * 512 + tid;
    const int d1 = d0 + 256;

    __shared__ float sacts[CAP_P][2 * RANK];    // 8 KB
    __shared__ float srout[CAP_P][2];
    __shared__ int   stok[CAP_P];

    const int* bp = bucketP + pb * CAP_P;
    if (tid < m) {
        int t = bp[tid];
        stok[tid] = t;
        srout[tid][0] = routing[2 * t];
        srout[tid][1] = routing[2 * t + 1];
    }
    __syncthreads();
    for (int idx = tid; idx < m * 8; idx += 256) {
        int tok = idx >> 3, q = idx & 7;
        float4 v = *(const float4*)(acts + (size_t)stok[tok] * 2 * RANK + q * 4);
        *(float4*)&sacts[tok][q * 4] = v;
    }
    __syncthreads();

    // wb cols for BOTH experts at BOTH d0,d1: 16 float4 = 64 VGPRs, reused over bucket
    const float4* p00 = (const float4*)(wb + ((size_t)e0 * NDIM + d0) * RANK);
    const float4* p01 = (const float4*)(wb + ((size_t)e0 * NDIM + d1) * RANK);
    const float4* p10 = (const float4*)(wb + ((size_t)e1 * NDIM + d0) * RANK);
    const float4* p11 = (const float4*)(wb + ((size_t)e1 * NDIM + d1) * RANK);
    const float4 a00 = p00[0], a01 = p00[1], a02 = p00[2], a03 = p00[3];
    const float4 b00 = p01[0], b01 = p01[1], b02 = p01[2], b03 = p01[3];
    const float4 a10 = p10[0], a11 = p10[1], a12 = p10[2], a13 = p10[3];
    const float4 b10 = p11[0], b11 = p11[1], b12 = p11[2], b13 = p11[3];

    #pragma unroll 2
    for (int i = 0; i < m; i++) {
        const float4* a = (const float4*)sacts[i];      // LDS broadcast reads
        float4 A0 = a[0], A1 = a[1], A2 = a[2], A3 = a[3];
        float4 B0 = a[4], B1 = a[5], B2 = a[6], B3 = a[7];
        float s0_0 = DOT4(a00, A0) + DOT4(a01, A1) + DOT4(a02, A2) + DOT4(a03, A3);
        float s1_0 = DOT4(a10, B0) + DOT4(a11, B1) + DOT4(a12, B2) + DOT4(a13, B3);
        float s0_1 = DOT4(b00, A0) + DOT4(b01, A1) + DOT4(b02, A2) + DOT4(b03, A3);
        float s1_1 = DOT4(b10, B0) + DOT4(b11, B1) + DOT4(b12, B2) + DOT4(b13, B3);
        const float r0 = srout[i][0], r1 = srout[i][1];
        float* op = out + (size_t)stok[i] * NDIM;
        __builtin_nontemporal_store(2.0f * (r0 * s0_0 + r1 * s1_0), op + d0);
        __builtin_nontemporal_store(2.0f * (r0 * s0_1 + r1 * s1_1), op + d1);
    }
}

extern "C" void kernel_launch(void* const* d_in, const int* in_sizes, int n_in,
                              void* d_out, int out_size, void* d_ws, size_t ws_size,
                              hipStream_t stream) {
    const float* x       = (const float*)d_in[0];
    const float* routing = (const float*)d_in[1];
    const int*   idxs    = (const int*)  d_in[2];
    const float* wa      = (const float*)d_in[3];
    const float* wb      = (const float*)d_in[4];
    float*       out     = (float*)d_out;

    // ws layout (bytes): [cntE 64][cntP @64][bucketE @2048 48KB]
    //                    [bucketP @51200 64KB][acts @116736 512KB]
    int*   cntE    = (int*)d_ws;
    int*   cntP    = (int*)((char*)d_ws + 64);
    int*   bucketE = (int*)((char*)d_ws + 2048);
    int*   bucketP = (int*)((char*)d_ws + 2048 + NEXP * CAP_E * 4);
    float* acts    = (float*)((char*)d_ws + 2048 + NEXP * CAP_E * 4
                                          + NEXP * NEXP * CAP_P * 4);

    k1_bucket <<<NEXP + NEXP * NEXP, 256, 0, stream>>>(idxs, cntE, cntP, bucketE, bucketP);
    k2_stage_a<<<NEXP * ETILES, 256, 0, stream>>>(x, wa, cntE, bucketE, acts);
    k3_stage_b<<<NEXP * NEXP * (NDIM / 512), 256, 0, stream>>>(routing, wb, cntP,
                                                               bucketP, acts, out);
}

// Round 13
// 126.955 us; speedup vs baseline: 1.2403x; 1.0363x over previous
//
#include <hip/hip_runtime.h>

// SparseLoRAMoE, expert-grouped, atomic-free.
// Round-13: k2 = whole-expert LDS residency. Six k2 designs (r3-r12) all
// pinned at ~35-45us; common factor = wa global loads in the inner loop,
// which the compiler refuses to pipeline (r11: VGPR 104 under a 256 cap).
// Fix: stage ALL of wa[e] (128KB, fits 160KB LDS) once per block, then a
// BARRIER-FREE inner loop reading wa via ds_read_b128 at linear lane*16B
// stride (bank-floor, conflict-free; compiler pipelines lgkmcnt well).
//   K2: 192 blocks (16 experts x 12 tiles) x 1024 thr (16 waves = 4/SIMD,
//       1 block/CU). Wave owns 4 entries x 16 ranks (r4 skeleton): acc[64],
//       x prefetched 1 K-step ahead, 16 LDS b128 reads + 256 FMA per step,
//       64-lane halving butterfly -> silu -> acts. VGPR ~125 fits (1024,4)'s
//       128 cap.
//   K1 (272 blocks): per-bucket scan of idxs, LDS counter (unchanged).
//   K3 (1024 blocks): 2 cols/thread, LDS-staged bucket, NT stores (unchanged).
// No zeroing, no atomics on out, bit-deterministic.

#define NDIM   2048
#define RANK   16
#define NEXP   16
#define TOKENS 4096
#define CAP_E  768      // per-expert entries; 12 tiles x 64
#define CAP_P  64       // per-pair tokens; mean 16, sd ~4 -> +12 sigma
#define TILE_E 64       // entries per K2 block (16 waves x 4)
#define ETILES (CAP_E / TILE_E)   // 12

#define DOT4(a, b) ((a).x*(b).x + (a).y*(b).y + (a).z*(b).z + (a).w*(b).w)

// ---------------- K1: bucketing, one block per bucket ----------------
__global__ __launch_bounds__(256) void k1_bucket(const int* __restrict__ idxs,
                                                 int* __restrict__ cntE,
                                                 int* __restrict__ cntP,
                                                 int* __restrict__ bucketE,
                                                 int* __restrict__ bucketP) {
    __shared__ int lcnt;
    const int bid = blockIdx.x;
    const int tid = threadIdx.x;
    if (tid == 0) lcnt = 0;
    __syncthreads();

    if (bid < NEXP) {                       // expert bucket: entries i with idxs[i]==e
        const int e = bid;
        const int4* p4 = (const int4*)idxs; // 8192 ints -> 2048 int4
        int* bk = bucketE + e * CAP_E;
        for (int i = tid; i < TOKENS * 2 / 4; i += 256) {
            int4 v = p4[i];
            if (v.x == e) { int p = atomicAdd(&lcnt, 1); if (p < CAP_E) bk[p] = 4*i+0; }
            if (v.y == e) { int p = atomicAdd(&lcnt, 1); if (p < CAP_E) bk[p] = 4*i+1; }
            if (v.z == e) { int p = atomicAdd(&lcnt, 1); if (p < CAP_E) bk[p] = 4*i+2; }
            if (v.w == e) { int p = atomicAdd(&lcnt, 1); if (p < CAP_E) bk[p] = 4*i+3; }
        }
        __syncthreads();
        if (tid == 0) cntE[e] = lcnt < CAP_E ? lcnt : CAP_E;
    } else {                                // pair bucket: tokens t with (e0,e1)==pb
        const int pb = bid - NEXP;
        const int e0 = pb >> 4, e1 = pb & (NEXP - 1);
        const int2* p2 = (const int2*)idxs;
        int* bk = bucketP + pb * CAP_P;
        for (int t = tid; t < TOKENS; t += 256) {
            int2 v = p2[t];
            if (v.x == e0 && v.y == e1) {
                int p = atomicAdd(&lcnt, 1);
                if (p < CAP_P) bk[p] = t;
            }
        }
        __syncthreads();
        if (tid == 0) cntP[pb] = lcnt < CAP_P ? lcnt : CAP_P;
    }
}

// ---------------- K2: stage A, whole wa[e] in LDS, barrier-free loop ----------------
__global__ __launch_bounds__(1024, 4) void k2_stage_a(const float* __restrict__ x,
                                                      const float* __restrict__ wa,
                                                      const int* __restrict__ cntE,
                                                      const int* __restrict__ bucketE,
                                                      float* __restrict__ acts) {
    const int e    = blockIdx.x & (NEXP - 1);
    const int tile = blockIdx.x >> 4;           // 0..ETILES-1
    int n = cntE[e];
    const int start = tile * TILE_E;
    int m = n - start;
    if (m <= 0) return;                         // uniform early-exit (before staging)
    if (m > TILE_E) m = TILE_E;

    __shared__ int sTok[TILE_E];
    __shared__ __align__(16) float was[RANK][NDIM];   // 128 KB: ALL of wa[e]

    const int tid  = threadIdx.x;
    const int lane = tid & 63;
    const int wave = tid >> 6;                  // 0..15

    if (tid < TILE_E) {
        int src = tid < m ? tid : m - 1;        // duplicate last entry in short tiles
        sTok[tid] = bucketE[e * CAP_E + start + src];
    }
    // ---- stage wa[e]: 8192 float4, 1024 threads, 8 coalesced iters ----
    {
        const float4* g = (const float4*)(wa + (size_t)e * RANK * NDIM);
        float4* l = (float4*)&was[0][0];
        #pragma unroll
        for (int it = 0; it < 8; it++)
            l[it * 1024 + tid] = g[it * 1024 + tid];
    }
    __syncthreads();                            // the only barrier

    // wave owns entries wave*4 .. wave*4+3; lanes split K (16B each)
    const float* xp[4];
    #pragma unroll
    for (int j = 0; j < 4; j++)
        xp[j] = x + (size_t)(sTok[wave * 4 + j] >> 1) * NDIM + lane * 4;

    float acc[64];
    #pragma unroll
    for (int i = 0; i < 64; i++) acc[i] = 0.f;

    float4 xc[4], xn[4];
    #pragma unroll
    for (int j = 0; j < 4; j++) xc[j] = *(const float4*)(xp[j]);

    for (int s = 0; s < NDIM / 256; s++) {      // 8 K-steps, barrier-free
        if (s < NDIM / 256 - 1) {               // prefetch next x step (HBM stream)
            #pragma unroll
            for (int j = 0; j < 4; j++)
                xn[j] = *(const float4*)(xp[j] + (s + 1) * 256);
        }
        const int off = s * 256 + lane * 4;
        #pragma unroll
        for (int r4 = 0; r4 < RANK; r4 += 4) {  // 4 rank-rows at a time from LDS
            float4 w0 = *(const float4*)&was[r4 + 0][off];
            float4 w1 = *(const float4*)&was[r4 + 1][off];
            float4 w2 = *(const float4*)&was[r4 + 2][off];
            float4 w3 = *(const float4*)&was[r4 + 3][off];
            acc[r4 + 0]      += DOT4(xc[0], w0);
            acc[r4 + 1]      += DOT4(xc[0], w1);
            acc[r4 + 2]      += DOT4(xc[0], w2);
            acc[r4 + 3]      += DOT4(xc[0], w3);
            acc[16 + r4 + 0] += DOT4(xc[1], w0);
            acc[16 + r4 + 1] += DOT4(xc[1], w1);
            acc[16 + r4 + 2] += DOT4(xc[1], w2);
            acc[16 + r4 + 3] += DOT4(xc[1], w3);
            acc[32 + r4 + 0] += DOT4(xc[2], w0);
            acc[32 + r4 + 1] += DOT4(xc[2], w1);
            acc[32 + r4 + 2] += DOT4(xc[2], w2);
            acc[32 + r4 + 3] += DOT4(xc[2], w3);
            acc[48 + r4 + 0] += DOT4(xc[3], w0);
            acc[48 + r4 + 1] += DOT4(xc[3], w1);
            acc[48 + r4 + 2] += DOT4(xc[3], w2);
            acc[48 + r4 + 3] += DOT4(xc[3], w3);
        }
        #pragma unroll
        for (int j = 0; j < 4; j++) xc[j] = xn[j];
    }

    // 64-value -> per-lane halving butterfly (all static indices)
    #pragma unroll
    for (int mw = 32; mw >= 1; mw >>= 1) {
        const bool up = (lane & mw) != 0;
        #pragma unroll
        for (int i = 0; i < mw; i++) {
            float lo = acc[i], hi = acc[i + mw];
            float mine = up ? hi : lo;
            float give = up ? lo : hi;
            acc[i] = mine + __shfl_xor(give, mw, 64);
        }
    }
    // lane l holds dot for entry sTok[wave*4 + (l>>4)], rank l&15
    float v  = acc[0];
    float sv = v / (1.f + __expf(-v));          // silu
    int ent  = sTok[(wave << 2) + (lane >> 4)];
    acts[(size_t)ent * RANK + (lane & 15)] = sv;
}

// ---------------- K3: stage B, 2 cols/thread, LDS-staged bucket, NT stores ----------------
__global__ __launch_bounds__(256, 2) void k3_stage_b(const float* __restrict__ routing,
                                                     const float* __restrict__ wb,
                                                     const int* __restrict__ cntP,
                                                     const int* __restrict__ bucketP,
                                                     const float* __restrict__ acts,
                                                     float* __restrict__ out) {
    const int pb  = blockIdx.x & (NEXP * NEXP - 1);
    const int dch = blockIdx.x >> 8;            // 0..3 (512 cols per block)
    int m = cntP[pb];
    if (m <= 0) return;
    if (m > CAP_P) m = CAP_P;
    const int e0 = pb >> 4;
    const int e1 = pb & (NEXP - 1);
    const int tid = threadIdx.x;
    const int d0 = dch * 512 + tid;
    const int d1 = d0 + 256;

    __shared__ float sacts[CAP_P][2 * RANK];    // 8 KB
    __shared__ float srout[CAP_P][2];
    __shared__ int   stok[CAP_P];

    const int* bp = bucketP + pb * CAP_P;
    if (tid < m) {
        int t = bp[tid];
        stok[tid] = t;
        srout[tid][0] = routing[2 * t];
        srout[tid][1] = routing[2 * t + 1];
    }
    __syncthreads();
    for (int idx = tid; idx < m * 8; idx += 256) {
        int tok = idx >> 3, q = idx & 7;
        float4 v = *(const float4*)(acts + (size_t)stok[tok] * 2 * RANK + q * 4);
        *(float4*)&sacts[tok][q * 4] = v;
    }
    __syncthreads();

    // wb cols for BOTH experts at BOTH d0,d1: 16 float4 = 64 VGPRs, reused over bucket
    const float4* p00 = (const float4*)(wb + ((size_t)e0 * NDIM + d0) * RANK);
    const float4* p01 = (const float4*)(wb + ((size_t)e0 * NDIM + d1) * RANK);
    const float4* p10 = (const float4*)(wb + ((size_t)e1 * NDIM + d0) * RANK);
    const float4* p11 = (const float4*)(wb + ((size_t)e1 * NDIM + d1) * RANK);
    const float4 a00 = p00[0], a01 = p00[1], a02 = p00[2], a03 = p00[3];
    const float4 b00 = p01[0], b01 = p01[1], b02 = p01[2], b03 = p01[3];
    const float4 a10 = p10[0], a11 = p10[1], a12 = p10[2], a13 = p10[3];
    const float4 b10 = p11[0], b11 = p11[1], b12 = p11[2], b13 = p11[3];

    #pragma unroll 2
    for (int i = 0; i < m; i++) {
        const float4* a = (const float4*)sacts[i];      // LDS broadcast reads
        float4 A0 = a[0], A1 = a[1], A2 = a[2], A3 = a[3];
        float4 B0 = a[4], B1 = a[5], B2 = a[6], B3 = a[7];
        float s0_0 = DOT4(a00, A0) + DOT4(a01, A1) + DOT4(a02, A2) + DOT4(a03, A3);
        float s1_0 = DOT4(a10, B0) + DOT4(a11, B1) + DOT4(a12, B2) + DOT4(a13, B3);
        float s0_1 = DOT4(b00, A0) + DOT4(b01, A1) + DOT4(b02, A2) + DOT4(b03, A3);
        float s1_1 = DOT4(b10, B0) + DOT4(b11, B1) + DOT4(b12, B2) + DOT4(b13, B3);
        const float r0 = srout[i][0], r1 = srout[i][1];
        float* op = out + (size_t)stok[i] * NDIM;
        __builtin_nontemporal_store(2.0f * (r0 * s0_0 + r1 * s1_0), op + d0);
        __builtin_nontemporal_store(2.0f * (r0 * s0_1 + r1 * s1_1), op + d1);
    }
}

extern "C" void kernel_launch(void* const* d_in, const int* in_sizes, int n_in,
                              void* d_out, int out_size, void* d_ws, size_t ws_size,
                              hipStream_t stream) {
    const float* x       = (const float*)d_in[0];
    const float* routing = (const float*)d_in[1];
    const int*   idxs    = (const int*)  d_in[2];
    const float* wa      = (const float*)d_in[3];
    const float* wb      = (const float*)d_in[4];
    float*       out     = (float*)d_out;

    // ws layout (bytes): [cntE 64][cntP @64][bucketE @2048 48KB]
    //                    [bucketP @51200 64KB][acts @116736 512KB]
    int*   cntE    = (int*)d_ws;
    int*   cntP    = (int*)((char*)d_ws + 64);
    int*   bucketE = (int*)((char*)d_ws + 2048);
    int*   bucketP = (int*)((char*)d_ws + 2048 + NEXP * CAP_E * 4);
    float* acts    = (float*)((char*)d_ws + 2048 + NEXP * CAP_E * 4
                                          + NEXP * NEXP * CAP_P * 4);

    k1_bucket <<<NEXP + NEXP * NEXP, 256, 0, stream>>>(idxs, cntE, cntP, bucketE, bucketP);
    k2_stage_a<<<NEXP * ETILES, 1024, 0, stream>>>(x, wa, cntE, bucketE, acts);
    k3_stage_b<<<NEXP * NEXP * (NDIM / 512), 256, 0, stream>>>(routing, wb, cntP,
                                                               bucketP, acts, out);
}